// Round 11
// baseline (476.726 us; speedup 1.0000x reference)
//
#include <hip/hip_runtime.h>
#include <math.h>

typedef _Float16 f16;
typedef _Float16 f16x2 __attribute__((ext_vector_type(2)));
typedef _Float16 f16x8 __attribute__((ext_vector_type(8)));
typedef float    f32x4 __attribute__((ext_vector_type(4)));

static constexpr int B = 2, H = 1024, W = 1024;
static constexpr int NCELL = 16;
static constexpr unsigned TOTAL1 = 2u*1024u*1024u*37u;   // 77,594,624

// ---- ws layout (bytes) ----
static constexpr size_t WT_OFF   = 0;                      // 10752 f16
static constexpr size_t WBT_OFF  = 21504;                  // 1024 f16
static constexpr size_t BIAS_OFF = 23552;                  // 80 f32
static constexpr size_t CWS_OFF  = 32768;                  // 512 cells * 4 sweeps * 1024 px * 18 f16
static constexpr size_t SUMS_OFF = CWS_OFF + (size_t)512*4*1024*18*2;  // 9728 f32
static constexpr size_t P1_OFF   = SUMS_OFF + 9728*4;              // 9216 f32
static constexpr size_t P2_OFF   = P1_OFF + 9216*4;                // 512 f32
static constexpr size_t RID_OFF  = P2_OFF + 512*4;                 // 1024 int
static constexpr size_t CID_OFF  = RID_OFF + 1024*4;               // 1024 int
static constexpr size_t FLAG_OFF = CID_OFF + 1024*4;               // 1 int

__device__ __forceinline__ int cell_of(const int* __restrict__ loc, int x) {
    int id = 0;
#pragma unroll
    for (int i = 1; i < NCELL; ++i) id = (loc[i] <= x) ? i : id;
    return id;
}

// ---- weight / bias prep + sums/flag zero (1 block) ----
__global__ __launch_bounds__(256)
void prep(const float* __restrict__ w1, const float* __restrict__ b1,
          const float* __restrict__ w2, const float* __restrict__ b2,
          const float* __restrict__ w3, const float* __restrict__ b3,
          const float* __restrict__ wb1, const float* __restrict__ bb1,
          const float* __restrict__ wb2, const float* __restrict__ bb2,
          f16* __restrict__ wT, f16* __restrict__ wbT, float* __restrict__ biasPad,
          float* __restrict__ sums, int* __restrict__ flag)
{
    const int tid = threadIdx.x;
    if (tid == 0) *flag = 0;
    for (int t = tid; t < 9728; t += 256) sums[t] = 0.f;
    // wT[cv][co(16)][k(224)] ; k = tap*24 + ci (ci<18 real)
    for (int t = tid; t < 10752; t += 256) {
        int cv = t / 3584, r = t - cv*3584;
        int co = r / 224,  k = r - co*224;
        float val = 0.f;
        if (k < 216 && co < 6) {
            int tap = k / 24, ci = k - tap*24;
            if (ci < 18) {
                const float* wsrc = cv==0 ? w1 : cv==1 ? w2 : w3;
                val = wsrc[(tap*18 + ci)*6 + co];
            }
        }
        wT[t] = (f16)val;
    }
    // wbT[nt(2)][col(16)][ci(32)] : rows ci>=18 are ZERO (A-side reads garbage there)
    for (int t = tid; t < 1024; t += 256) {
        int nt = t >> 9, r = t & 511;
        int colv = r >> 5, ci = r & 31;
        int co2 = nt*16 + colv;
        float val = 0.f;
        if (ci < 18) {
            if (co2 < 18) val = wb1[ci*18 + co2];
            else if (co2 == 18) val = wb2[ci];
        }
        wbT[t] = (f16)val;
    }
    // biases: [0..47] conv (3x16), [48..63] bb1[0..15], [64..79] {bb1[16],bb1[17],bb2[0],0...}
    for (int t = tid; t < 80; t += 256) {
        float val = 0.f;
        if (t < 48) { int cv = t >> 4, co = t & 15;
            const float* bp = cv==0 ? b1 : cv==1 ? b2 : b3;
            val = (co < 6) ? bp[co] : 0.f; }
        else if (t < 64) val = bb1[t - 48];
        else { int c = t - 64;
            val = (c==0) ? bb1[16] : (c==1) ? bb1[17] : (c==2) ? bb2[0] : 0.f; }
        biasPad[t] = val;
    }
}

// ---- fully-fused cell kernel: one block = one 64x64 cell, 1024 threads ----
__global__ __launch_bounds__(1024)
void conv_cell(const float* __restrict__ in,
               const f16* __restrict__ wT, const f16* __restrict__ wbT,
               const float* __restrict__ biasPad,
               const int* __restrict__ row_loc, const int* __restrict__ col_loc,
               f16* __restrict__ c_ws, float* __restrict__ sums,
               float* __restrict__ out, int* __restrict__ flag)
{
    __shared__ __align__(16) f16 s_a[22*70*24];   // 73,920 B ; overlaid as ct[1024][18] per sweep
    __shared__ float s_red[16][19];
    __shared__ float s_pool[19];

    const int tid = threadIdx.x;
    const int bx  = blockIdx.x;                 // 0..511
    const int b   = bx >> 8, rem = bx & 255;
    const int h0  = (rem >> 4) * 64, w0 = (rem & 15) * 64;

    const int lane = tid & 63, wv = tid >> 6;
    const int lm = lane & 15, g = lane >> 4;
    const int rq = wv & 3, cg = wv >> 2;

    // block==cell check (exact): cell boundaries coincide with this 64x64 region
    const int rid = cell_of(row_loc, h0), cid = cell_of(col_loc, w0);
    const bool uniformB = (row_loc[rid] == h0) && (row_loc[rid+1] == h0 + 64) &&
                          (col_loc[cid] == w0) && (col_loc[cid+1] == w0 + 64);

    const f16x8 wbf0 = *(const f16x8*)(wbT + lm*32 + g*8);
    const f16x8 wbf1 = *(const f16x8*)(wbT + (16 + lm)*32 + g*8);
    const float bs0 = biasPad[lm], bs1 = biasPad[16 + lm], bs2 = biasPad[32 + lm];
    const float bb0 = biasPad[48 + lm], bb1v = biasPad[64 + lm];
    const bool act = (lm < 6);
    const f32x4 z4 = (f32x4){0.f,0.f,0.f,0.f};

    float ps0 = 0.f, ps1 = 0.f;

#pragma unroll 1
    for (int s = 0; s < 4; ++s) {
        // ---- stage 22x70 px (ci padded 18->24) as f16 : R5-pattern ILP loads ----
        const int gh0 = h0 + s*16 - 3, gw0 = w0 - 3;
        const bool interior = (gh0 >= 0) && (gh0 + 22 <= H) && (gw0 >= 0) && (gw0 + 70 <= W);
#pragma unroll
        for (int k = 0; k < 2; ++k) {
            const int p = tid + k*1024;
            if (p < 1540) {
                const int r = p / 70, cc = p - r*70;
                const int gh = gh0 + r, gw = gw0 + cc;
                const bool ok = interior || ((unsigned)gh < (unsigned)H && (unsigned)gw < (unsigned)W);
                float2 L[9];
                if (ok) {
                    const float* sp = in + ((size_t)((size_t)b*H + gh)*W + gw)*18;
#pragma unroll
                    for (int j = 0; j < 9; ++j) L[j] = *(const float2*)(sp + 2*j);
                } else {
#pragma unroll
                    for (int j = 0; j < 9; ++j) L[j] = make_float2(0.f, 0.f);
                }
                f16x8 A0, A1, A2;
#pragma unroll
                for (int j = 0; j < 4; ++j) { A0[2*j] = (f16)L[j].x;   A0[2*j+1] = (f16)L[j].y; }
#pragma unroll
                for (int j = 0; j < 4; ++j) { A1[2*j] = (f16)L[4+j].x; A1[2*j+1] = (f16)L[4+j].y; }
                A2[0] = (f16)L[8].x; A2[1] = (f16)L[8].y;
#pragma unroll
                for (int j = 2; j < 8; ++j) A2[j] = (f16)0.f;
                *(f16x8*)&s_a[p*24 + 0]  = A0;
                *(f16x8*)&s_a[p*24 + 8]  = A1;
                *(f16x8*)&s_a[p*24 + 16] = A2;
            }
        }
        __syncthreads();

        // ---- conv MFMAs (validated math, SC=70) ----
        f32x4 acc[3][4];
#pragma unroll
        for (int cv = 0; cv < 3; ++cv)
#pragma unroll
            for (int mt = 0; mt < 4; ++mt) acc[cv][mt] = z4;

#pragma unroll
        for (int cv = 0; cv < 3; ++cv) {
            const int d = cv + 1;
            const f16* wtc = wT + cv*3584 + lm*224 + g*8;
            f16x8 bf[7];
#pragma unroll
            for (int kb = 0; kb < 7; ++kb) bf[kb] = *(const f16x8*)(wtc + kb*32);
            int tofs[7];
#pragma unroll
            for (int kb = 0; kb < 7; ++kb) {
                int i8 = kb*4 + g; if (i8 > 26) i8 = 26;   // clamp pad (B rows zero there)
                int tap = i8 / 3;
                int ci0 = (i8 - tap*3) * 8;
                int ky = tap / 3, kx = tap - ky*3;
                tofs[kb] = (((ky-1)*d)*70 + (kx-1)*d)*24 + ci0;
            }
#pragma unroll
            for (int mt = 0; mt < 4; ++mt) {
                const int py = rq*4 + mt;
                const int base = ((py + 3)*70 + cg*16 + lm + 3) * 24;
                f32x4 a = acc[cv][mt];
#pragma unroll
                for (int kb = 0; kb < 7; ++kb) {
                    f16x8 af = *(const f16x8*)&s_a[base + tofs[kb]];
                    a = __builtin_amdgcn_mfma_f32_16x16x32_f16(af, bf[kb], a, 0, 0, 0);
                }
                acc[cv][mt] = a;
            }
        }
        __syncthreads();           // done reading s_a -> overlay ct

        // ---- epilogue: relu(c)+bias into ct[1024][18] (sweep-local [16 rows][64 cols]) ----
        f16* ct = s_a;
#pragma unroll
        for (int cv = 0; cv < 3; ++cv) {
            const float bv = cv==0 ? bs0 : cv==1 ? bs1 : bs2;
#pragma unroll
            for (int mt = 0; mt < 4; ++mt) {
                const int py = rq*4 + mt;
#pragma unroll
                for (int r = 0; r < 4; ++r) {
                    float val = fmaxf(acc[cv][mt][r] + bv, 0.f);
                    const int px = cg*16 + g*4 + r;             // C row=(lane>>4)*4+reg
                    if (act) ct[(py*64 + px)*18 + cv*6 + lm] = (f16)val;
                }
            }
        }
        __syncthreads();           // ct ready

        // ---- copy ct -> c_ws ([cell][sweep][1024][18]) ----
        {
            const f16x8* src = (const f16x8*)ct;               // 2304 x 16B
            f16x8* dst = (f16x8*)(c_ws + ((size_t)bx*4 + s)*1024*18);
#pragma unroll
            for (int k = 0; k < 3; ++k) {
                const int i = tid + k*1024;
                if (i < 2304) dst[i] = src[i];
            }
        }

        // ---- 1x1 convs as 2 MFMAs per mtile ----
        const unsigned* ctu = (const unsigned*)ct;
        f32x4 acc2[4][2];
#pragma unroll
        for (int mt = 0; mt < 4; ++mt) {
            const int py = rq*4 + mt;
            const int p = py*64 + cg*16 + lm;
            const int du = (p*36 + g*16) >> 2;
            union { f16x8 v; unsigned u[4]; } A;
#pragma unroll
            for (int j = 0; j < 4; ++j) A.u[j] = ctu[du + j];
            acc2[mt][0] = __builtin_amdgcn_mfma_f32_16x16x32_f16(A.v, wbf0, z4, 0, 0, 0);
            acc2[mt][1] = __builtin_amdgcn_mfma_f32_16x16x32_f16(A.v, wbf1, z4, 0, 0, 0);
        }

        // ---- pooling partials ----
        if (uniformB) {
#pragma unroll
            for (int mt = 0; mt < 4; ++mt)
#pragma unroll
                for (int r = 0; r < 4; ++r) {
                    float v0 = fmaxf(acc2[mt][0][r] + bb0, 0.f);
                    float t1 = acc2[mt][1][r] + bb1v;
                    float v1x = (lm < 2) ? fmaxf(t1, 0.f) : t1;
                    ps0 += v0; ps1 += v1x;
                }
        } else {
            // generic grid: per-pixel atomics into global cell sums
#pragma unroll
            for (int mt = 0; mt < 4; ++mt) {
                const int py = rq*4 + mt;
                const int prid = cell_of(row_loc, h0 + s*16 + py);
#pragma unroll
                for (int r = 0; r < 4; ++r) {
                    const int px = cg*16 + g*4 + r;
                    const int cell = b*256 + prid*16 + cell_of(col_loc, w0 + px);
                    float v0 = fmaxf(acc2[mt][0][r] + bb0, 0.f);
                    atomicAdd(&sums[cell*19 + lm], v0);
                    if (lm < 3) {
                        float t1 = acc2[mt][1][r] + bb1v;
                        float v1x = (lm < 2) ? fmaxf(t1, 0.f) : t1;
                        atomicAdd(&sums[cell*19 + 16 + lm], v1x);
                    }
                }
            }
        }
        __syncthreads();           // protect ct before next sweep restages
    }

    if (!uniformB) {
        if (tid == 0) *flag = 1;   // fallback kernels will finish the job
        return;
    }

    // ---- block-local pooling finale ----
    ps0 += __shfl_xor(ps0, 16); ps0 += __shfl_xor(ps0, 32);
    ps1 += __shfl_xor(ps1, 16); ps1 += __shfl_xor(ps1, 32);
    if (lane < 16) s_red[wv][lane] = ps0;
    if (lane < 3)  s_red[wv][16 + lane] = ps1;
    __syncthreads();
    if (tid < 19) {
        float ssum = 0.f;
#pragma unroll
        for (int wvi = 0; wvi < 16; ++wvi) ssum += s_red[wvi][tid];
        atomicAdd(&sums[(b*256 + rid*16 + cid)*19 + tid], ssum);   // keep global sums valid (mixed case)
        float mean = ssum * (1.f/4096.f);
        s_pool[tid] = (tid == 18) ? (1.f / (1.f + __expf(-mean))) : mean;
    }
    __syncthreads();

    // ---- final output write: 4 px/thread, full 148 B coverage per pixel ----
    const f16* cbase = c_ws + (size_t)bx * 4096 * 18;
    const float p2v = s_pool[18];
#pragma unroll
    for (int it = 0; it < 4; ++it) {
        const int lp = tid + it*1024;
        const int row = lp >> 6, col = lp & 63;
        const int sw = row >> 4, rw = row & 15;
        const unsigned* cu = (const unsigned*)(cbase + ((size_t)sw*1024 + rw*64 + col)*18);
        float ov[37];
#pragma unroll
        for (int ch = 0; ch < 18; ++ch) ov[ch] = s_pool[ch];
#pragma unroll
        for (int jj = 0; jj < 9; ++jj) {
            f16x2 hv = __builtin_bit_cast(f16x2, cu[jj]);
            ov[18 + 2*jj]     = (float)hv[0];
            ov[18 + 2*jj + 1] = (float)hv[1];
        }
        const size_t pix = ((size_t)(b*H + h0 + row))*W + (w0 + col);
        float* op = out + pix*37;
#pragma unroll
        for (int q = 0; q < 9; ++q)
            *(float4*)(op + q*4) = make_float4(ov[4*q], ov[4*q+1], ov[4*q+2], ov[4*q+3]);
        op[36] = p2v;
        out[(size_t)TOTAL1 + pix] = p2v;
    }
}

// ---- gated fallback: pooled finalize (runs only if flag set) ----
__global__ __launch_bounds__(256)
void finalize(const int* __restrict__ row_loc, const int* __restrict__ col_loc,
              const float* __restrict__ sums,
              float* __restrict__ pooled1, float* __restrict__ pooled2,
              int* __restrict__ row_ids, int* __restrict__ col_ids,
              const int* __restrict__ flag)
{
    if (*flag == 0) return;
    __shared__ int rcnt[NCELL], ccnt[NCELL];
    const int tid = threadIdx.x;
    if (tid < NCELL) { rcnt[tid] = 0; ccnt[tid] = 0; }
    __syncthreads();
    for (int h = tid; h < H; h += 256) {
        int r = cell_of(row_loc, h); row_ids[h] = r; atomicAdd(&rcnt[r], 1);
    }
    for (int w = tid; w < W; w += 256) {
        int cc = cell_of(col_loc, w); col_ids[w] = cc; atomicAdd(&ccnt[cc], 1);
    }
    __syncthreads();
    for (int t = tid; t < B*256*18; t += 256) {
        int cell = t / 18, ch = t - cell*18;
        int rid = (cell >> 4) & 15, cid = cell & 15;
        int cnt = rcnt[rid] * ccnt[cid];
        pooled1[t] = (cnt > 0) ? sums[cell*19 + ch] / (float)cnt : 0.f;
    }
    for (int t = tid; t < B*256; t += 256) {
        int rid = (t >> 4) & 15, cid = t & 15;
        int cnt = rcnt[rid] * ccnt[cid];
        float v = (cnt > 0) ? sums[t*19 + 18] / (float)cnt : 0.f;
        pooled2[t] = 1.f / (1.f + __expf(-v));
    }
}

// ---- gated fallback: row-centric assembly (runs only if flag set) ----
__global__ __launch_bounds__(256)
void assemble(const f16* __restrict__ c_ws, const float* __restrict__ pooled1,
              const float* __restrict__ pooled2, const int* __restrict__ row_ids,
              const int* __restrict__ col_ids, float* __restrict__ out,
              const int* __restrict__ flag)
{
    if (*flag == 0) return;
    __shared__ __align__(16) f16 s_c[1024*18];      // px-major [w][ch]
    __shared__ float s_p1[16*18];
    __shared__ float s_p2[16];
    __shared__ unsigned char s_cid[1024];

    const int tid = threadIdx.x;
    const int bx  = blockIdx.x;                 // = b*1024 + h
    const int b   = bx >> 10, h = bx & 1023;
    const int br  = h >> 6, sw = (h >> 4) & 3, rw = h & 15;

    // gather row from 16 cell-chunks (each 64px*18ch = 2304 B contiguous)
    float4* dstv = (float4*)s_c;
#pragma unroll
    for (int k = 0; k < 9; ++k) {
        const int j = tid + k*256;              // j < 2304
        const int t = j / 144, i = j - t*144;
        const size_t base = (((size_t)(b*256 + br*16 + t)*4 + sw)*1024 + rw*64)*18;
        dstv[j] = ((const float4*)(c_ws + base))[i];
    }
    const int rid = row_ids[h];
    for (int i = tid; i < 288; i += 256) {
        int cid = i / 18, ch = i - cid*18;
        s_p1[i] = pooled1[((size_t)(b*256 + rid*16 + cid))*18 + ch];
    }
    if (tid < 16) s_p2[tid] = pooled2[b*256 + rid*16 + tid];
    for (int i = tid; i < 1024; i += 256) s_cid[i] = (unsigned char)col_ids[i];
    __syncthreads();

    float* orow = out + (size_t)bx * (1024*37);
    for (int i4 = tid; i4 < 1024*37/4; i4 += 256) {
        const int o0 = i4*4;
        float v[4];
#pragma unroll
        for (int j = 0; j < 4; ++j) {
            const int o = o0 + j;
            const unsigned pix = (unsigned)o / 37u;
            const int ch = o - (int)pix*37;
            const int cid = s_cid[pix];
            float val;
            if (ch < 18)       val = s_p1[cid*18 + ch];
            else if (ch < 36)  val = (float)s_c[pix*18 + (ch - 18)];
            else               val = s_p2[cid];
            v[j] = val;
        }
        *(float4*)(orow + o0) = make_float4(v[0], v[1], v[2], v[3]);
    }
    float* o2 = out + (size_t)TOTAL1 + (size_t)bx * 1024;
    {
        const int p0 = tid * 4;
        float4 v = make_float4(s_p2[s_cid[p0]], s_p2[s_cid[p0+1]],
                               s_p2[s_cid[p0+2]], s_p2[s_cid[p0+3]]);
        *(float4*)(o2 + p0) = v;
    }
}

extern "C" void kernel_launch(void* const* d_in, const int* in_sizes, int n_in,
                              void* d_out, int out_size, void* d_ws, size_t ws_size,
                              hipStream_t stream)
{
    (void)in_sizes; (void)n_in; (void)out_size; (void)ws_size;
    const float* in      = (const float*)d_in[0];
    const int*   row_loc = (const int*)d_in[1];
    const int*   col_loc = (const int*)d_in[2];
    const float *w1 = (const float*)d_in[3],  *b1  = (const float*)d_in[4];
    const float *w2 = (const float*)d_in[5],  *b2  = (const float*)d_in[6];
    const float *w3 = (const float*)d_in[7],  *b3  = (const float*)d_in[8];
    const float *wb1= (const float*)d_in[9],  *bb1 = (const float*)d_in[10];
    const float *wb2= (const float*)d_in[11], *bb2 = (const float*)d_in[12];

    float* out = (float*)d_out;
    char*  ws  = (char*)d_ws;

    f16*   wT      = (f16*)(ws + WT_OFF);
    f16*   wbT     = (f16*)(ws + WBT_OFF);
    float* biasPad = (float*)(ws + BIAS_OFF);
    f16*   c_ws    = (f16*)(ws + CWS_OFF);
    float* sums    = (float*)(ws + SUMS_OFF);
    float* pooled1 = (float*)(ws + P1_OFF);
    float* pooled2 = (float*)(ws + P2_OFF);
    int*   row_ids = (int*)(ws + RID_OFF);
    int*   col_ids = (int*)(ws + CID_OFF);
    int*   flag    = (int*)(ws + FLAG_OFF);

    prep<<<dim3(1), dim3(256), 0, stream>>>(w1, b1, w2, b2, w3, b3,
                                            wb1, bb1, wb2, bb2, wT, wbT, biasPad,
                                            sums, flag);

    conv_cell<<<dim3(512), dim3(1024), 0, stream>>>(
        in, wT, wbT, biasPad, row_loc, col_loc, c_ws, sums, out, flag);

    finalize<<<dim3(1), dim3(256), 0, stream>>>(
        row_loc, col_loc, sums, pooled1, pooled2, row_ids, col_ids, flag);

    assemble<<<dim3(B*H), dim3(256), 0, stream>>>(
        c_ws, pooled1, pooled2, row_ids, col_ids, out, flag);
}

// Round 12
// 221.512 us; speedup vs baseline: 2.1521x; 2.1521x over previous
//
#include <hip/hip_runtime.h>
#include <math.h>

typedef _Float16 f16;
typedef _Float16 f16x2 __attribute__((ext_vector_type(2)));
typedef _Float16 f16x8 __attribute__((ext_vector_type(8)));
typedef float    f32x4 __attribute__((ext_vector_type(4)));

static constexpr int B = 2, H = 1024, W = 1024;
static constexpr int NCELL = 16;
static constexpr unsigned TOTAL1 = 2u*1024u*1024u*37u;   // 77,594,624

// ---- ws layout (bytes) ----
static constexpr size_t WT_OFF   = 0;                      // 10752 f16
static constexpr size_t WBT_OFF  = 21504;                  // 1024 f16
static constexpr size_t BIAS_OFF = 23552;                  // 80 f32
static constexpr size_t CWS_OFF  = 32768;                  // 512 cells * 8 sweeps * 512 px * 18 f16
static constexpr size_t SUMS_OFF = CWS_OFF + (size_t)512*8*512*18*2;  // 9728 f32
static constexpr size_t P1_OFF   = SUMS_OFF + 9728*4;              // 9216 f32
static constexpr size_t P2_OFF   = P1_OFF + 9216*4;                // 512 f32
static constexpr size_t RID_OFF  = P2_OFF + 512*4;                 // 1024 int
static constexpr size_t CID_OFF  = RID_OFF + 1024*4;               // 1024 int
static constexpr size_t FLAG_OFF = CID_OFF + 1024*4;               // 1 int

__device__ __forceinline__ int cell_of(const int* __restrict__ loc, int x) {
    int id = 0;
#pragma unroll
    for (int i = 1; i < NCELL; ++i) id = (loc[i] <= x) ? i : id;
    return id;
}

// ---- weight / bias prep + sums/flag zero (1 block) ----
__global__ __launch_bounds__(256)
void prep(const float* __restrict__ w1, const float* __restrict__ b1,
          const float* __restrict__ w2, const float* __restrict__ b2,
          const float* __restrict__ w3, const float* __restrict__ b3,
          const float* __restrict__ wb1, const float* __restrict__ bb1,
          const float* __restrict__ wb2, const float* __restrict__ bb2,
          f16* __restrict__ wT, f16* __restrict__ wbT, float* __restrict__ biasPad,
          float* __restrict__ sums, int* __restrict__ flag)
{
    const int tid = threadIdx.x;
    if (tid == 0) *flag = 0;
    for (int t = tid; t < 9728; t += 256) sums[t] = 0.f;
    for (int t = tid; t < 10752; t += 256) {
        int cv = t / 3584, r = t - cv*3584;
        int co = r / 224,  k = r - co*224;
        float val = 0.f;
        if (k < 216 && co < 6) {
            int tap = k / 24, ci = k - tap*24;
            if (ci < 18) {
                const float* wsrc = cv==0 ? w1 : cv==1 ? w2 : w3;
                val = wsrc[(tap*18 + ci)*6 + co];
            }
        }
        wT[t] = (f16)val;
    }
    for (int t = tid; t < 1024; t += 256) {
        int nt = t >> 9, r = t & 511;
        int colv = r >> 5, ci = r & 31;
        int co2 = nt*16 + colv;
        float val = 0.f;
        if (ci < 18) {
            if (co2 < 18) val = wb1[ci*18 + co2];
            else if (co2 == 18) val = wb2[ci];
        }
        wbT[t] = (f16)val;
    }
    for (int t = tid; t < 80; t += 256) {
        float val = 0.f;
        if (t < 48) { int cv = t >> 4, co = t & 15;
            const float* bp = cv==0 ? b1 : cv==1 ? b2 : b3;
            val = (co < 6) ? bp[co] : 0.f; }
        else if (t < 64) val = bb1[t - 48];
        else { int c = t - 64;
            val = (c==0) ? bb1[16] : (c==1) ? bb1[17] : (c==2) ? bb2[0] : 0.f; }
        biasPad[t] = val;
    }
}

// ---- fully-fused cell kernel: one block = one 64x64 cell, 512 threads, 8 sweeps of 8 rows ----
__global__ __launch_bounds__(512, 1)
void conv_cell(const float* __restrict__ in,
               const f16* __restrict__ wT, const f16* __restrict__ wbT,
               const float* __restrict__ biasPad,
               const int* __restrict__ row_loc, const int* __restrict__ col_loc,
               f16* __restrict__ c_ws, float* __restrict__ sums,
               float* __restrict__ out, int* __restrict__ flag)
{
    __shared__ __align__(16) f16 s_a[14*70*24];   // 47,040 B ; overlaid as ct[512][18] per sweep
    __shared__ float s_red[8][19];
    __shared__ float s_pool[19];

    const int tid = threadIdx.x;
    const int bx  = blockIdx.x;                 // 0..511
    const int b   = bx >> 8, rem = bx & 255;
    const int h0  = (rem >> 4) * 64, w0 = (rem & 15) * 64;

    const int lane = tid & 63, wv = tid >> 6;   // 8 waves; wave wv owns row wv of each sweep
    const int lm = lane & 15, g = lane >> 4;

    const int rid = cell_of(row_loc, h0), cid = cell_of(col_loc, w0);
    const bool uniformB = (row_loc[rid] == h0) && (row_loc[rid+1] == h0 + 64) &&
                          (col_loc[cid] == w0) && (col_loc[cid+1] == w0 + 64);

    const f16x8 wbf0 = *(const f16x8*)(wbT + lm*32 + g*8);
    const f16x8 wbf1 = *(const f16x8*)(wbT + (16 + lm)*32 + g*8);
    const float bs0 = biasPad[lm], bs1 = biasPad[16 + lm], bs2 = biasPad[32 + lm];
    const float bb0 = biasPad[48 + lm], bb1v = biasPad[64 + lm];
    const bool act = (lm < 6);
    const f32x4 z4 = (f32x4){0.f,0.f,0.f,0.f};

    float ps0 = 0.f, ps1 = 0.f;

#pragma unroll 1
    for (int s = 0; s < 8; ++s) {
        // ---- stage 14x70 px (ci padded 18->24) as f16 : R5-pattern ILP loads ----
        const int gh0 = h0 + s*8 - 3, gw0 = w0 - 3;
        const bool interior = (gh0 >= 0) && (gh0 + 14 <= H) && (gw0 >= 0) && (gw0 + 70 <= W);
#pragma unroll
        for (int k = 0; k < 2; ++k) {
            const int p = tid + k*512;
            if (p < 980) {
                const int r = p / 70, cc = p - r*70;
                const int gh = gh0 + r, gw = gw0 + cc;
                const bool ok = interior || ((unsigned)gh < (unsigned)H && (unsigned)gw < (unsigned)W);
                float2 L[9];
                if (ok) {
                    const float* sp = in + ((size_t)((size_t)b*H + gh)*W + gw)*18;
#pragma unroll
                    for (int j = 0; j < 9; ++j) L[j] = *(const float2*)(sp + 2*j);
                } else {
#pragma unroll
                    for (int j = 0; j < 9; ++j) L[j] = make_float2(0.f, 0.f);
                }
                f16x8 A0, A1, A2;
#pragma unroll
                for (int j = 0; j < 4; ++j) { A0[2*j] = (f16)L[j].x;   A0[2*j+1] = (f16)L[j].y; }
#pragma unroll
                for (int j = 0; j < 4; ++j) { A1[2*j] = (f16)L[4+j].x; A1[2*j+1] = (f16)L[4+j].y; }
                A2[0] = (f16)L[8].x; A2[1] = (f16)L[8].y;
#pragma unroll
                for (int j = 2; j < 8; ++j) A2[j] = (f16)0.f;
                *(f16x8*)&s_a[p*24 + 0]  = A0;
                *(f16x8*)&s_a[p*24 + 8]  = A1;
                *(f16x8*)&s_a[p*24 + 16] = A2;
            }
        }
        __syncthreads();

        // ---- conv MFMAs (validated math, SC=70; py = wv, col-group = mt) ----
        f32x4 acc[3][4];
#pragma unroll
        for (int cv = 0; cv < 3; ++cv)
#pragma unroll
            for (int mt = 0; mt < 4; ++mt) acc[cv][mt] = z4;

#pragma unroll
        for (int cv = 0; cv < 3; ++cv) {
            const int d = cv + 1;
            const f16* wtc = wT + cv*3584 + lm*224 + g*8;
            f16x8 bf[7];
#pragma unroll
            for (int kb = 0; kb < 7; ++kb) bf[kb] = *(const f16x8*)(wtc + kb*32);
            int tofs[7];
#pragma unroll
            for (int kb = 0; kb < 7; ++kb) {
                int i8 = kb*4 + g; if (i8 > 26) i8 = 26;   // clamp pad (B rows zero there)
                int tap = i8 / 3;
                int ci0 = (i8 - tap*3) * 8;
                int ky = tap / 3, kx = tap - ky*3;
                tofs[kb] = (((ky-1)*d)*70 + (kx-1)*d)*24 + ci0;
            }
#pragma unroll
            for (int mt = 0; mt < 4; ++mt) {
                const int base = ((wv + 3)*70 + mt*16 + lm + 3) * 24;
                f32x4 a = acc[cv][mt];
#pragma unroll
                for (int kb = 0; kb < 7; ++kb) {
                    f16x8 af = *(const f16x8*)&s_a[base + tofs[kb]];
                    a = __builtin_amdgcn_mfma_f32_16x16x32_f16(af, bf[kb], a, 0, 0, 0);
                }
                acc[cv][mt] = a;
            }
        }
        __syncthreads();           // done reading s_a -> overlay ct

        // ---- epilogue: relu(c)+bias into ct[512][18] (sweep-local [8 rows][64 cols]) ----
        f16* ct = s_a;
#pragma unroll
        for (int cv = 0; cv < 3; ++cv) {
            const float bv = cv==0 ? bs0 : cv==1 ? bs1 : bs2;
#pragma unroll
            for (int mt = 0; mt < 4; ++mt) {
#pragma unroll
                for (int r = 0; r < 4; ++r) {
                    float val = fmaxf(acc[cv][mt][r] + bv, 0.f);
                    const int col = mt*16 + g*4 + r;            // C row=(lane>>4)*4+reg
                    if (act) ct[(wv*64 + col)*18 + cv*6 + lm] = (f16)val;
                }
            }
        }
        __syncthreads();           // ct ready

        // ---- copy ct -> c_ws ([cell][sweep(8)][512][18]) ----
        {
            const f16x8* src = (const f16x8*)ct;               // 1152 x 16B
            f16x8* dst = (f16x8*)(c_ws + ((size_t)bx*8 + s)*512*18);
#pragma unroll
            for (int k = 0; k < 3; ++k) {
                const int i = tid + k*512;
                if (i < 1152) dst[i] = src[i];
            }
        }

        // ---- 1x1 convs as 2 MFMAs per mtile ----
        const unsigned* ctu = (const unsigned*)ct;
        f32x4 acc2[4][2];
#pragma unroll
        for (int mt = 0; mt < 4; ++mt) {
            const int p = wv*64 + mt*16 + lm;
            const int du = (p*36 + g*16) >> 2;
            union { f16x8 v; unsigned u[4]; } A;
#pragma unroll
            for (int j = 0; j < 4; ++j) A.u[j] = ctu[du + j];
            acc2[mt][0] = __builtin_amdgcn_mfma_f32_16x16x32_f16(A.v, wbf0, z4, 0, 0, 0);
            acc2[mt][1] = __builtin_amdgcn_mfma_f32_16x16x32_f16(A.v, wbf1, z4, 0, 0, 0);
        }

        // ---- pooling partials ----
        if (uniformB) {
#pragma unroll
            for (int mt = 0; mt < 4; ++mt)
#pragma unroll
                for (int r = 0; r < 4; ++r) {
                    float v0 = fmaxf(acc2[mt][0][r] + bb0, 0.f);
                    float t1 = acc2[mt][1][r] + bb1v;
                    float v1x = (lm < 2) ? fmaxf(t1, 0.f) : t1;
                    ps0 += v0; ps1 += v1x;
                }
        } else {
#pragma unroll
            for (int mt = 0; mt < 4; ++mt) {
                const int prid = cell_of(row_loc, h0 + s*8 + wv);
#pragma unroll
                for (int r = 0; r < 4; ++r) {
                    const int px = mt*16 + g*4 + r;
                    const int cell = b*256 + prid*16 + cell_of(col_loc, w0 + px);
                    float v0 = fmaxf(acc2[mt][0][r] + bb0, 0.f);
                    atomicAdd(&sums[cell*19 + lm], v0);
                    if (lm < 3) {
                        float t1 = acc2[mt][1][r] + bb1v;
                        float v1x = (lm < 2) ? fmaxf(t1, 0.f) : t1;
                        atomicAdd(&sums[cell*19 + 16 + lm], v1x);
                    }
                }
            }
        }
        __syncthreads();           // protect ct before next sweep restages
    }

    if (!uniformB) {
        if (tid == 0) *flag = 1;   // fallback kernels finish the job
        return;
    }

    // ---- block-local pooling finale ----
    ps0 += __shfl_xor(ps0, 16); ps0 += __shfl_xor(ps0, 32);
    ps1 += __shfl_xor(ps1, 16); ps1 += __shfl_xor(ps1, 32);
    if (lane < 16) s_red[wv][lane] = ps0;
    if (lane < 3)  s_red[wv][16 + lane] = ps1;
    __syncthreads();
    if (tid < 19) {
        float ssum = 0.f;
#pragma unroll
        for (int wvi = 0; wvi < 8; ++wvi) ssum += s_red[wvi][tid];
        atomicAdd(&sums[(b*256 + rid*16 + cid)*19 + tid], ssum);   // keep global sums valid
        float mean = ssum * (1.f/4096.f);
        s_pool[tid] = (tid == 18) ? (1.f / (1.f + __expf(-mean))) : mean;
    }
    __syncthreads();

    // ---- final output: per sweep, reload c chunk to LDS, write coalesced float4 rows ----
    const float p2v = s_pool[18];
#pragma unroll 1
    for (int sw = 0; sw < 8; ++sw) {
        const f16x8* src = (const f16x8*)(c_ws + ((size_t)bx*8 + sw)*512*18);
        f16x8* dst = (f16x8*)s_a;
#pragma unroll
        for (int k = 0; k < 3; ++k) {
            const int i = tid + k*512;
            if (i < 1152) dst[i] = src[i];
        }
        __syncthreads();
        const f16* cl = s_a;
        for (int j = tid; j < 4736; j += 512) {      // 8 rows x 592 float4
            const int rowl = j / 592;
            const int jo = j - rowl*592;
            float v[4];
#pragma unroll
            for (int q = 0; q < 4; ++q) {
                const int o = jo*4 + q;              // 0..2367
                const unsigned pl = (unsigned)o / 37u;
                const int ch = o - (int)pl*37;
                float val;
                if (ch < 18)      val = s_pool[ch];
                else if (ch < 36) val = (float)cl[(rowl*64 + (int)pl)*18 + ch - 18];
                else              val = p2v;
                v[q] = val;
            }
            float* orow = out + ((size_t)(b*H + h0 + sw*8 + rowl)*W + w0)*37;
            *(float4*)(orow + jo*4) = make_float4(v[0], v[1], v[2], v[3]);
        }
        {
            const int rowl = tid >> 6, col = tid & 63;
            out[(size_t)TOTAL1 + (size_t)(b*H + h0 + sw*8 + rowl)*W + w0 + col] = p2v;
        }
        __syncthreads();
    }
}

// ---- gated fallback: pooled finalize (runs only if flag set) ----
__global__ __launch_bounds__(256)
void finalize(const int* __restrict__ row_loc, const int* __restrict__ col_loc,
              const float* __restrict__ sums,
              float* __restrict__ pooled1, float* __restrict__ pooled2,
              int* __restrict__ row_ids, int* __restrict__ col_ids,
              const int* __restrict__ flag)
{
    if (*flag == 0) return;
    __shared__ int rcnt[NCELL], ccnt[NCELL];
    const int tid = threadIdx.x;
    if (tid < NCELL) { rcnt[tid] = 0; ccnt[tid] = 0; }
    __syncthreads();
    for (int h = tid; h < H; h += 256) {
        int r = cell_of(row_loc, h); row_ids[h] = r; atomicAdd(&rcnt[r], 1);
    }
    for (int w = tid; w < W; w += 256) {
        int cc = cell_of(col_loc, w); col_ids[w] = cc; atomicAdd(&ccnt[cc], 1);
    }
    __syncthreads();
    for (int t = tid; t < B*256*18; t += 256) {
        int cell = t / 18, ch = t - cell*18;
        int rid = (cell >> 4) & 15, cid = cell & 15;
        int cnt = rcnt[rid] * ccnt[cid];
        pooled1[t] = (cnt > 0) ? sums[cell*19 + ch] / (float)cnt : 0.f;
    }
    for (int t = tid; t < B*256; t += 256) {
        int rid = (t >> 4) & 15, cid = t & 15;
        int cnt = rcnt[rid] * ccnt[cid];
        float v = (cnt > 0) ? sums[t*19 + 18] / (float)cnt : 0.f;
        pooled2[t] = 1.f / (1.f + __expf(-v));
    }
}

// ---- gated fallback: row-centric assembly (runs only if flag set) ----
__global__ __launch_bounds__(256)
void assemble(const f16* __restrict__ c_ws, const float* __restrict__ pooled1,
              const float* __restrict__ pooled2, const int* __restrict__ row_ids,
              const int* __restrict__ col_ids, float* __restrict__ out,
              const int* __restrict__ flag)
{
    if (*flag == 0) return;
    __shared__ __align__(16) f16 s_c[1024*18];      // px-major [w][ch]
    __shared__ float s_p1[16*18];
    __shared__ float s_p2[16];
    __shared__ unsigned char s_cid[1024];

    const int tid = threadIdx.x;
    const int bx  = blockIdx.x;                 // = b*1024 + h
    const int b   = bx >> 10, h = bx & 1023;
    const int br  = h >> 6, sw = (h >> 3) & 7, rw = h & 7;

    // gather row from 16 cell-chunks (each 64px*18ch = 2304 B = 144 float4 contiguous)
    float4* dstv = (float4*)s_c;
#pragma unroll
    for (int k = 0; k < 9; ++k) {
        const int j = tid + k*256;              // j < 2304
        const int t = j / 144, i = j - t*144;
        const size_t base = (((size_t)(b*256 + br*16 + t)*8 + sw)*512 + rw*64)*18;
        dstv[j] = ((const float4*)(c_ws + base))[i];
    }
    const int rid = row_ids[h];
    for (int i = tid; i < 288; i += 256) {
        int cid = i / 18, ch = i - cid*18;
        s_p1[i] = pooled1[((size_t)(b*256 + rid*16 + cid))*18 + ch];
    }
    if (tid < 16) s_p2[tid] = pooled2[b*256 + rid*16 + tid];
    for (int i = tid; i < 1024; i += 256) s_cid[i] = (unsigned char)col_ids[i];
    __syncthreads();

    float* orow = out + (size_t)bx * (1024*37);
    for (int i4 = tid; i4 < 1024*37/4; i4 += 256) {
        const int o0 = i4*4;
        float v[4];
#pragma unroll
        for (int j = 0; j < 4; ++j) {
            const int o = o0 + j;
            const unsigned pix = (unsigned)o / 37u;
            const int ch = o - (int)pix*37;
            const int cid = s_cid[pix];
            float val;
            if (ch < 18)       val = s_p1[cid*18 + ch];
            else if (ch < 36)  val = (float)s_c[pix*18 + (ch - 18)];
            else               val = s_p2[cid];
            v[j] = val;
        }
        *(float4*)(orow + o0) = make_float4(v[0], v[1], v[2], v[3]);
    }
    float* o2 = out + (size_t)TOTAL1 + (size_t)bx * 1024;
    {
        const int p0 = tid * 4;
        float4 v = make_float4(s_p2[s_cid[p0]], s_p2[s_cid[p0+1]],
                               s_p2[s_cid[p0+2]], s_p2[s_cid[p0+3]]);
        *(float4*)(o2 + p0) = v;
    }
}

extern "C" void kernel_launch(void* const* d_in, const int* in_sizes, int n_in,
                              void* d_out, int out_size, void* d_ws, size_t ws_size,
                              hipStream_t stream)
{
    (void)in_sizes; (void)n_in; (void)out_size; (void)ws_size;
    const float* in      = (const float*)d_in[0];
    const int*   row_loc = (const int*)d_in[1];
    const int*   col_loc = (const int*)d_in[2];
    const float *w1 = (const float*)d_in[3],  *b1  = (const float*)d_in[4];
    const float *w2 = (const float*)d_in[5],  *b2  = (const float*)d_in[6];
    const float *w3 = (const float*)d_in[7],  *b3  = (const float*)d_in[8];
    const float *wb1= (const float*)d_in[9],  *bb1 = (const float*)d_in[10];
    const float *wb2= (const float*)d_in[11], *bb2 = (const float*)d_in[12];

    float* out = (float*)d_out;
    char*  ws  = (char*)d_ws;

    f16*   wT      = (f16*)(ws + WT_OFF);
    f16*   wbT     = (f16*)(ws + WBT_OFF);
    float* biasPad = (float*)(ws + BIAS_OFF);
    f16*   c_ws    = (f16*)(ws + CWS_OFF);
    float* sums    = (float*)(ws + SUMS_OFF);
    float* pooled1 = (float*)(ws + P1_OFF);
    float* pooled2 = (float*)(ws + P2_OFF);
    int*   row_ids = (int*)(ws + RID_OFF);
    int*   col_ids = (int*)(ws + CID_OFF);
    int*   flag    = (int*)(ws + FLAG_OFF);

    prep<<<dim3(1), dim3(256), 0, stream>>>(w1, b1, w2, b2, w3, b3,
                                            wb1, bb1, wb2, bb2, wT, wbT, biasPad,
                                            sums, flag);

    conv_cell<<<dim3(512), dim3(512), 0, stream>>>(
        in, wT, wbT, biasPad, row_loc, col_loc, c_ws, sums, out, flag);

    finalize<<<dim3(1), dim3(256), 0, stream>>>(
        row_loc, col_loc, sums, pooled1, pooled2, row_ids, col_ids, flag);

    assemble<<<dim3(B*H), dim3(256), 0, stream>>>(
        c_ws, pooled1, pooled2, row_ids, col_ids, out, flag);
}

// Round 13
// 209.700 us; speedup vs baseline: 2.2734x; 1.0563x over previous
//
#include <hip/hip_runtime.h>
#include <math.h>

typedef _Float16 f16;
typedef _Float16 f16x2 __attribute__((ext_vector_type(2)));
typedef _Float16 f16x8 __attribute__((ext_vector_type(8)));
typedef float    f32x4 __attribute__((ext_vector_type(4)));

static constexpr int B = 2, H = 1024, W = 1024;
static constexpr int NCELL = 16;
static constexpr unsigned TOTAL1 = 2u*1024u*1024u*37u;   // 77,594,624

// ---- ws layout (bytes) ----
static constexpr size_t WT_OFF   = 0;                      // 10752 f16
static constexpr size_t WBT_OFF  = 21504;                  // 1024 f16
static constexpr size_t BIAS_OFF = 23552;                  // 80 f32
static constexpr size_t CWS_OFF  = 32768;                  // 8192 tiles * 9216 B (tiled c)
static constexpr size_t SUMS_OFF = CWS_OFF + (size_t)8192*9216;    // 9728 f32
static constexpr size_t P1_OFF   = SUMS_OFF + 9728*4;              // 9216 f32
static constexpr size_t P2_OFF   = P1_OFF + 9216*4;                // 512 f32
static constexpr size_t RID_OFF  = P2_OFF + 512*4;                 // 1024 int
static constexpr size_t CID_OFF  = RID_OFF + 1024*4;               // 1024 int

// SoA A-tile regions: chunk c of pixel px lives at REG_OFS(c) + 16*px.
__device__ __forceinline__ int reg_ofs(int c) {
    return c == 0 ? 0 : (c == 1 ? 7856 : 15712);
}

__device__ __forceinline__ int cell_of(const int* __restrict__ loc, int x) {
    int id = 0;
#pragma unroll
    for (int i = 1; i < NCELL; ++i) id = (loc[i] <= x) ? i : id;
    return id;
}

// ---- weight / bias prep + sums zero (1 block) ----
__global__ __launch_bounds__(256)
void prep(const float* __restrict__ w1, const float* __restrict__ b1,
          const float* __restrict__ w2, const float* __restrict__ b2,
          const float* __restrict__ w3, const float* __restrict__ b3,
          const float* __restrict__ wb1, const float* __restrict__ bb1,
          const float* __restrict__ wb2, const float* __restrict__ bb2,
          f16* __restrict__ wT, f16* __restrict__ wbT, float* __restrict__ biasPad,
          float* __restrict__ sums)
{
    const int tid = threadIdx.x;
    for (int t = tid; t < 9728; t += 256) sums[t] = 0.f;
    // wT[cv][co(16)][k(224)] ; k = tap*24 + ci (ci<18 real)
    for (int t = tid; t < 10752; t += 256) {
        int cv = t / 3584, r = t - cv*3584;
        int co = r / 224,  k = r - co*224;
        float val = 0.f;
        if (k < 216 && co < 6) {
            int tap = k / 24, ci = k - tap*24;
            if (ci < 18) {
                const float* wsrc = cv==0 ? w1 : cv==1 ? w2 : w3;
                val = wsrc[(tap*18 + ci)*6 + co];
            }
        }
        wT[t] = (f16)val;
    }
    // wbT[nt(2)][col(16)][ci(32)] : rows ci>=18 are ZERO (A-side reads garbage there)
    for (int t = tid; t < 1024; t += 256) {
        int nt = t >> 9, r = t & 511;
        int colv = r >> 5, ci = r & 31;
        int co2 = nt*16 + colv;
        float val = 0.f;
        if (ci < 18) {
            if (co2 < 18) val = wb1[ci*18 + co2];
            else if (co2 == 18) val = wb2[ci];
        }
        wbT[t] = (f16)val;
    }
    // biases: [0..47] conv (3x16), [48..63] bb1[0..15], [64..79] {bb1[16],bb1[17],bb2[0],0...}
    for (int t = tid; t < 80; t += 256) {
        float val = 0.f;
        if (t < 48) { int cv = t >> 4, co = t & 15;
            const float* bp = cv==0 ? b1 : cv==1 ? b2 : b3;
            val = (co < 6) ? bp[co] : 0.f; }
        else if (t < 64) val = bb1[t - 48];
        else { int c = t - 64;
            val = (c==0) ? bb1[16] : (c==1) ? bb1[17] : (c==2) ? bb2[0] : 0.f; }
        biasPad[t] = val;
    }
}

// ---- fused conv (MFMA) + 1x1 + pooling partial sums : 16x16 tile, 256 threads ----
__global__ __launch_bounds__(256)
void conv_mfma(const float* __restrict__ in,
               const f16* __restrict__ wT, const f16* __restrict__ wbT,
               const float* __restrict__ biasPad,
               const int* __restrict__ row_loc, const int* __restrict__ col_loc,
               f16* __restrict__ c_ws, float* __restrict__ sums)
{
    __shared__ __align__(16) f16 s_a[11728];      // 23,456 B SoA A-tile ; overlay ct[256][18]
    __shared__ float s_red[4][19];

    const int tid = threadIdx.x;
    const int bx  = blockIdx.x;
    const int b   = bx >> 12, rem = bx & 4095;
    const int h0  = (rem >> 6) * 16, w0 = (rem & 63) * 16;

    // ---- stage input tile (22x22 px, ci padded 18->24) as f16 : 1 px/thread, ILP loads ----
    const int gh0 = h0 - 3, gw0 = w0 - 3;
    const bool interior = (gh0 >= 0) && (h0 + 19 <= H) && (gw0 >= 0) && (w0 + 19 <= W);
#pragma unroll
    for (int k = 0; k < 2; ++k) {
        const int p = tid + k*256;
        if (p < 484) {
            const int r = p / 22, cc = p - r*22;
            const int gh = gh0 + r, gw = gw0 + cc;
            const bool ok = interior || ((unsigned)gh < (unsigned)H && (unsigned)gw < (unsigned)W);
            float2 L[9];
            if (ok) {
                const float* sp = in + ((size_t)((size_t)b*H + gh)*W + gw)*18;
#pragma unroll
                for (int j = 0; j < 9; ++j) L[j] = *(const float2*)(sp + 2*j);
            } else {
#pragma unroll
                for (int j = 0; j < 9; ++j) L[j] = make_float2(0.f, 0.f);
            }
            f16x8 A0, A1, A2;
#pragma unroll
            for (int j = 0; j < 4; ++j) { A0[2*j] = (f16)L[j].x;   A0[2*j+1] = (f16)L[j].y; }
#pragma unroll
            for (int j = 0; j < 4; ++j) { A1[2*j] = (f16)L[4+j].x; A1[2*j+1] = (f16)L[4+j].y; }
            A2[0] = (f16)L[8].x; A2[1] = (f16)L[8].y;
#pragma unroll
            for (int j = 2; j < 8; ++j) A2[j] = (f16)0.f;
            char* base = (char*)s_a;
            *(f16x8*)(base + 0     + p*16) = A0;
            *(f16x8*)(base + 7856  + p*16) = A1;
            *(f16x8*)(base + 15712 + p*16) = A2;
        }
    }
    __syncthreads();

    const int lane = tid & 63, wv = tid >> 6;
    const int lm = lane & 15, g = lane >> 4;

    f32x4 acc[3][4];
#pragma unroll
    for (int cv = 0; cv < 3; ++cv)
#pragma unroll
        for (int mt = 0; mt < 4; ++mt) acc[cv][mt] = (f32x4){0.f,0.f,0.f,0.f};

#pragma unroll
    for (int cv = 0; cv < 3; ++cv) {
        const int d = cv + 1;
        const f16* wtc = wT + cv*3584 + lm*224 + g*8;
        f16x8 bf[7];
#pragma unroll
        for (int kb = 0; kb < 7; ++kb) bf[kb] = *(const f16x8*)(wtc + kb*32);
        int rofs[7];   // region base + pixel-delta*16, lane-dependent via g
#pragma unroll
        for (int kb = 0; kb < 7; ++kb) {
            int i8 = kb*4 + g; if (i8 > 26) i8 = 26;   // clamp pad (B rows zero there)
            int tap = i8 / 3;
            int cic = i8 - tap*3;                      // chunk index {0,1,2}
            int ky = tap / 3, kx = tap - ky*3;
            rofs[kb] = reg_ofs(cic) + (((ky-1)*d)*22 + (kx-1)*d)*16;
        }
#pragma unroll
        for (int mt = 0; mt < 4; ++mt) {
            const int py = wv*4 + mt;
            const int pxb = ((py + 3)*22 + lm + 3) * 16;
            f32x4 a = acc[cv][mt];
#pragma unroll
            for (int kb = 0; kb < 7; ++kb) {
                f16x8 af = *(const f16x8*)((const char*)s_a + pxb + rofs[kb]);
                a = __builtin_amdgcn_mfma_f32_16x16x32_f16(af, bf[kb], a, 0, 0, 0);
            }
            acc[cv][mt] = a;
        }
    }

    __syncthreads();            // done reading s_a -> safe to overlay ct
    f16* ct = s_a;              // ct[256][18] contiguous (matches global tiled layout)
    const float bs0 = biasPad[lm], bs1 = biasPad[16 + lm], bs2 = biasPad[32 + lm];
    const bool act = (lm < 6);
#pragma unroll
    for (int cv = 0; cv < 3; ++cv) {
        const float bv = cv==0 ? bs0 : cv==1 ? bs1 : bs2;
#pragma unroll
        for (int mt = 0; mt < 4; ++mt) {
            const int py = wv*4 + mt;
#pragma unroll
            for (int r = 0; r < 4; ++r) {
                float val = fmaxf(acc[cv][mt][r] + bv, 0.f);   // relu(c)
                const int px = g*4 + r;                         // C row = (lane>>4)*4+reg
                if (act) ct[(py*16 + px)*18 + cv*6 + lm] = (f16)val;
            }
        }
    }
    __syncthreads();            // ct ready

    // ---- cooperative coalesced copy ct -> c_ws (tiled [bx][256][18]) ----
    {
        const f16x8* src = (const f16x8*)ct;                   // 576 x 16B
        f16x8* dst = (f16x8*)(c_ws + (size_t)bx * 4608);
#pragma unroll
        for (int k = 0; k < 3; ++k) {
            const int i = tid + k*256;
            if (i < 576) dst[i] = src[i];
        }
    }

    // ---- 1x1 convs as 2 MFMAs per mtile (A k>=18 reads neighbor garbage, B rows zero) ----
    const f16x8 wbf0 = *(const f16x8*)(wbT + lm*32 + g*8);
    const f16x8 wbf1 = *(const f16x8*)(wbT + (16 + lm)*32 + g*8);
    const f32x4 z4 = (f32x4){0.f,0.f,0.f,0.f};
    const unsigned* ctu = (const unsigned*)ct;
    f32x4 acc2[4][2];
#pragma unroll
    for (int mt = 0; mt < 4; ++mt) {
        const int py = wv*4 + mt;
        const int du = ((py*16 + lm)*36 + g*16) >> 2;   // dword index, 4B-aligned
        union { f16x8 v; unsigned u[4]; } A;
#pragma unroll
        for (int j = 0; j < 4; ++j) A.u[j] = ctu[du + j];
        acc2[mt][0] = __builtin_amdgcn_mfma_f32_16x16x32_f16(A.v, wbf0, z4, 0, 0, 0);
        acc2[mt][1] = __builtin_amdgcn_mfma_f32_16x16x32_f16(A.v, wbf1, z4, 0, 0, 0);
    }

    // ---- pooling partial sums ----
    const float bb0 = biasPad[48 + lm];
    const float bb1v = biasPad[64 + lm];
    const int rid0 = cell_of(row_loc, h0), rid1 = cell_of(row_loc, h0 + 15);
    const int cid0 = cell_of(col_loc, w0), cid1 = cell_of(col_loc, w0 + 15);
    if (rid0 == rid1 && cid0 == cid1) {
        float ps0 = 0.f, ps1 = 0.f;
#pragma unroll
        for (int mt = 0; mt < 4; ++mt)
#pragma unroll
            for (int r = 0; r < 4; ++r) {
                float v0 = fmaxf(acc2[mt][0][r] + bb0, 0.f);
                float t1 = acc2[mt][1][r] + bb1v;
                float v1x = (lm < 2) ? fmaxf(t1, 0.f) : t1;
                ps0 += v0; ps1 += v1x;
            }
        ps0 += __shfl_xor(ps0, 16); ps0 += __shfl_xor(ps0, 32);
        ps1 += __shfl_xor(ps1, 16); ps1 += __shfl_xor(ps1, 32);
        if (lane < 16) s_red[wv][lane] = ps0;
        if (lane < 3)  s_red[wv][16 + lane] = ps1;
        __syncthreads();
        if (tid < 19) {
            float s = s_red[0][tid] + s_red[1][tid] + s_red[2][tid] + s_red[3][tid];
            const int cell = b*256 + rid0*16 + cid0;
            atomicAdd(&sums[cell*19 + tid], s);
        }
    } else {
#pragma unroll
        for (int mt = 0; mt < 4; ++mt) {
            const int py = wv*4 + mt;
            const int rid = cell_of(row_loc, h0 + py);
#pragma unroll
            for (int r = 0; r < 4; ++r) {
                const int px = g*4 + r;
                const int cell = b*256 + rid*16 + cell_of(col_loc, w0 + px);
                float v0 = fmaxf(acc2[mt][0][r] + bb0, 0.f);
                atomicAdd(&sums[cell*19 + lm], v0);
                if (lm < 3) {
                    float t1 = acc2[mt][1][r] + bb1v;
                    float v1x = (lm < 2) ? fmaxf(t1, 0.f) : t1;
                    atomicAdd(&sums[cell*19 + 16 + lm], v1x);
                }
            }
        }
    }
}

__global__ __launch_bounds__(256)
void finalize(const int* __restrict__ row_loc, const int* __restrict__ col_loc,
              const float* __restrict__ sums,
              float* __restrict__ pooled1, float* __restrict__ pooled2,
              int* __restrict__ row_ids, int* __restrict__ col_ids)
{
    __shared__ int rcnt[NCELL], ccnt[NCELL];
    const int tid = threadIdx.x;
    if (tid < NCELL) { rcnt[tid] = 0; ccnt[tid] = 0; }
    __syncthreads();
    for (int h = tid; h < H; h += 256) {
        int r = cell_of(row_loc, h); row_ids[h] = r; atomicAdd(&rcnt[r], 1);
    }
    for (int w = tid; w < W; w += 256) {
        int cc = cell_of(col_loc, w); col_ids[w] = cc; atomicAdd(&ccnt[cc], 1);
    }
    __syncthreads();
    for (int t = tid; t < B*256*18; t += 256) {
        int cell = t / 18, ch = t - cell*18;
        int rid = (cell >> 4) & 15, cid = cell & 15;
        int cnt = rcnt[rid] * ccnt[cid];
        pooled1[t] = (cnt > 0) ? sums[cell*19 + ch] / (float)cnt : 0.f;
    }
    for (int t = tid; t < B*256; t += 256) {
        int rid = (t >> 4) & 15, cid = t & 15;
        int cnt = rcnt[rid] * ccnt[cid];
        float v = (cnt > 0) ? sums[t*19 + 18] / (float)cnt : 0.f;
        pooled2[t] = 1.f / (1.f + __expf(-v));
    }
}

// ---- row-centric output assembly: one block per (b,h) row ----
__global__ __launch_bounds__(256)
void assemble(const f16* __restrict__ c_ws, const float* __restrict__ pooled1,
              const float* __restrict__ pooled2, const int* __restrict__ row_ids,
              const int* __restrict__ col_ids, float* __restrict__ out)
{
    __shared__ __align__(16) f16 s_c[1024*18];      // 36,864 B, px-major [w][ch]
    __shared__ float s_p1[16*18];
    __shared__ float s_p2[16];
    __shared__ unsigned char s_cid[1024];

    const int tid = threadIdx.x;
    const int bx  = blockIdx.x;                 // = b*1024 + h
    const int b   = bx >> 10, h = bx & 1023;

    // gather this row's c from 64 tiled chunks (each 16px*18ch = 576 B contiguous)
    const int tbase = b*4096 + (h >> 4)*64;
    const size_t rofs = (size_t)(h & 15) * 576;
    const char* cbase = (const char*)c_ws;
    float4* dstv = (float4*)s_c;
#pragma unroll
    for (int k = 0; k < 9; ++k) {
        const int j = tid + k*256;              // j < 2304
        const int t = j / 36, i = j - t*36;
        const float4 v = *(const float4*)(cbase + (size_t)(tbase + t)*9216 + rofs + (size_t)i*16);
        dstv[j] = v;
    }
    const int rid = row_ids[h];
    for (int i = tid; i < 288; i += 256) {
        int cid = i / 18, ch = i - cid*18;
        s_p1[i] = pooled1[((size_t)(b*256 + rid*16 + cid))*18 + ch];
    }
    if (tid < 16) s_p2[tid] = pooled2[b*256 + rid*16 + tid];
    for (int i = tid; i < 1024; i += 256) s_cid[i] = (unsigned char)col_ids[i];
    __syncthreads();

    float* orow = out + (size_t)bx * (1024*37);
    for (int i4 = tid; i4 < 1024*37/4; i4 += 256) {
        const int o0 = i4*4;
        float v[4];
#pragma unroll
        for (int j = 0; j < 4; ++j) {
            const int o = o0 + j;
            const unsigned pix = (unsigned)o / 37u;
            const int ch = o - (int)pix*37;
            const int cid = s_cid[pix];
            float val;
            if (ch < 18)       val = s_p1[cid*18 + ch];
            else if (ch < 36)  val = (float)s_c[pix*18 + (ch - 18)];
            else               val = s_p2[cid];
            v[j] = val;
        }
        *(float4*)(orow + o0) = make_float4(v[0], v[1], v[2], v[3]);
    }
    float* o2 = out + (size_t)TOTAL1 + (size_t)bx * 1024;
    {
        const int p0 = tid * 4;
        float4 v = make_float4(s_p2[s_cid[p0]], s_p2[s_cid[p0+1]],
                               s_p2[s_cid[p0+2]], s_p2[s_cid[p0+3]]);
        *(float4*)(o2 + p0) = v;
    }
}

extern "C" void kernel_launch(void* const* d_in, const int* in_sizes, int n_in,
                              void* d_out, int out_size, void* d_ws, size_t ws_size,
                              hipStream_t stream)
{
    (void)in_sizes; (void)n_in; (void)out_size; (void)ws_size;
    const float* in      = (const float*)d_in[0];
    const int*   row_loc = (const int*)d_in[1];
    const int*   col_loc = (const int*)d_in[2];
    const float *w1 = (const float*)d_in[3],  *b1  = (const float*)d_in[4];
    const float *w2 = (const float*)d_in[5],  *b2  = (const float*)d_in[6];
    const float *w3 = (const float*)d_in[7],  *b3  = (const float*)d_in[8];
    const float *wb1= (const float*)d_in[9],  *bb1 = (const float*)d_in[10];
    const float *wb2= (const float*)d_in[11], *bb2 = (const float*)d_in[12];

    float* out = (float*)d_out;
    char*  ws  = (char*)d_ws;

    f16*   wT      = (f16*)(ws + WT_OFF);
    f16*   wbT     = (f16*)(ws + WBT_OFF);
    float* biasPad = (float*)(ws + BIAS_OFF);
    f16*   c_ws    = (f16*)(ws + CWS_OFF);
    float* sums    = (float*)(ws + SUMS_OFF);
    float* pooled1 = (float*)(ws + P1_OFF);
    float* pooled2 = (float*)(ws + P2_OFF);
    int*   row_ids = (int*)(ws + RID_OFF);
    int*   col_ids = (int*)(ws + CID_OFF);

    prep<<<dim3(1), dim3(256), 0, stream>>>(w1, b1, w2, b2, w3, b3,
                                            wb1, bb1, wb2, bb2, wT, wbT, biasPad, sums);

    conv_mfma<<<dim3(8192), dim3(256), 0, stream>>>(
        in, wT, wbT, biasPad, row_loc, col_loc, c_ws, sums);

    finalize<<<dim3(1), dim3(256), 0, stream>>>(
        row_loc, col_loc, sums, pooled1, pooled2, row_ids, col_ids);

    assemble<<<dim3(B*H), dim3(256), 0, stream>>>(
        c_ws, pooled1, pooled2, row_ids, col_ids, out);
}